// Round 1
// baseline (480.065 us; speedup 1.0000x reference)
//
#include <hip/hip_runtime.h>

// LSTM: B=4096, T=2048, I=1, H=16. 16 lanes per sequence (lane j owns h[j],c[j]
// and gate rows j, j+16, j+32, j+48), 4 sequences per wave64. All cross-lane
// traffic via DPP (quad_perm / row mirrors) - zero LDS. fp32 throughout.

constexpr int T_LEN = 2048;

template<int CTRL>
__device__ __forceinline__ float dpp_mov(float v) {
  return __int_as_float(__builtin_amdgcn_update_dpp(
      0, __float_as_int(v), CTRL, 0xF, 0xF, true));
}

__device__ __forceinline__ float fexp2(float x) { return __builtin_amdgcn_exp2f(x); }
__device__ __forceinline__ float frcp(float x)  { return __builtin_amdgcn_rcpf(x); }
// sigmoid(x) = 1/(1+2^(-x*log2e))
__device__ __forceinline__ float fsig(float x)  { return frcp(1.0f + fexp2(x * -1.4426950408889634f)); }
// tanh(x) = 2/(1+2^(-2x*log2e)) - 1
__device__ __forceinline__ float ftanh_(float x){ return fmaf(frcp(1.0f + fexp2(x * -2.8853900817779268f)), 2.0f, -1.0f); }

// DPP ctrl values:
//  0xB1 = quad_perm [1,0,3,2]  -> lane ^ 1
//  0x4E = quad_perm [2,3,0,1]  -> lane ^ 2
//  0x1B = quad_perm [3,2,1,0]  -> lane ^ 3
//  0x141 = row_half_mirror     -> lane ^ 7  (within 8)
//  0x140 = row_mirror          -> lane ^ 15 (within 16)

// One xor-walk round: rotate h copy by CTRL, accumulate term m into 4 gate accs.
#define HROT(CTRL, M) do {                                                 \
    hc = dpp_mov<CTRL>(hc);                                                \
    a0 = fmaf(hc, w0[M], a0); a1 = fmaf(hc, w1[M], a1);                    \
    a2 = fmaf(hc, w2[M], a2); a3 = fmaf(hc, w3[M], a3);                    \
  } while (0)

// One LSTM timestep (S = step-in-block, compile-time literal).
#define GSTEP(S) do {                                                      \
    const float xt = xv[S];                                                \
    float a0 = fmaf(xt, wih0, bb0);                                        \
    float a1 = fmaf(xt, wih1, bb1);                                        \
    float a2 = fmaf(xt, wih2, bb2);                                        \
    float a3 = fmaf(xt, wih3, bb3);                                        \
    float hc = h;                                                          \
    a0 = fmaf(hc, w0[0], a0); a1 = fmaf(hc, w1[0], a1);                    \
    a2 = fmaf(hc, w2[0], a2); a3 = fmaf(hc, w3[0], a3);                    \
    HROT(0xB1, 1);  HROT(0x1B, 2);  HROT(0xB1, 3);  HROT(0x141, 4);        \
    HROT(0xB1, 5);  HROT(0x1B, 6);  HROT(0xB1, 7);  HROT(0x140, 8);        \
    HROT(0xB1, 9);  HROT(0x1B, 10); HROT(0xB1, 11); HROT(0x141, 12);       \
    HROT(0xB1, 13); HROT(0x1B, 14); HROT(0xB1, 15);                        \
    const float iv = fsig(a0);                                             \
    const float fv = fsig(a1);                                             \
    const float gv = ftanh_(a2);                                           \
    const float ov = fsig(a3);                                             \
    c = fmaf(fv, c, iv * gv);                                              \
    h = ov * ftanh_(c);                                                    \
    float p = h * wfcj;                                                    \
    p += dpp_mov<0xB1>(p);                                                 \
    p += dpp_mov<0x4E>(p);                                                 \
    p += dpp_mov<0x141>(p);                                                \
    p += dpp_mov<0x140>(p);                                                \
    ykeep = (j == (S)) ? (p + bfc) : ykeep;                                \
  } while (0)

__global__ __launch_bounds__(256) void lstm_fused_kernel(
    const float* __restrict__ x, const float* __restrict__ W_ih,
    const float* __restrict__ W_hh, const float* __restrict__ b_ih,
    const float* __restrict__ b_hh, const float* __restrict__ W_fc,
    const float* __restrict__ b_fc, float* __restrict__ out)
{
  const int tid  = blockIdx.x * blockDim.x + threadIdx.x;
  const int wave = tid >> 6;          // 0..1023
  const int lane = tid & 63;
  const int grp  = (lane >> 4) & 3;   // sequence-within-wave
  const int j    = lane & 15;         // h index owned by this lane
  const int b    = wave * 4 + grp;    // sequence id 0..4095

  const float* __restrict__ xb = x   + (size_t)b * T_LEN;
  float*       __restrict__ yb = out + (size_t)b * T_LEN;

  const int r0 = j, r1 = j + 16, r2 = j + 32, r3 = j + 48;

  // Pre-gathered, xor-permuted W_hh rows: w'[m] = W_hh[r][j ^ m]
  float w0[16], w1[16], w2[16], w3[16];
#pragma unroll
  for (int m = 0; m < 16; ++m) {
    const int k = j ^ m;
    w0[m] = W_hh[r0 * 16 + k];
    w1[m] = W_hh[r1 * 16 + k];
    w2[m] = W_hh[r2 * 16 + k];
    w3[m] = W_hh[r3 * 16 + k];
  }
  const float wih0 = W_ih[r0], wih1 = W_ih[r1], wih2 = W_ih[r2], wih3 = W_ih[r3];
  const float bb0 = b_ih[r0] + b_hh[r0];
  const float bb1 = b_ih[r1] + b_hh[r1];
  const float bb2 = b_ih[r2] + b_hh[r2];
  const float bb3 = b_ih[r3] + b_hh[r3];
  const float wfcj = W_fc[j];
  const float bfc  = b_fc[0];

  float h = 0.0f, c = 0.0f, ykeep = 0.0f;

  // x for current 16-step block, in registers (group-uniform loads -> cache bcast)
  float xv[16];
  {
    const float4* p4 = reinterpret_cast<const float4*>(xb);
    float4 v0 = p4[0], v1 = p4[1], v2 = p4[2], v3 = p4[3];
    xv[0]=v0.x; xv[1]=v0.y; xv[2]=v0.z; xv[3]=v0.w;
    xv[4]=v1.x; xv[5]=v1.y; xv[6]=v1.z; xv[7]=v1.w;
    xv[8]=v2.x; xv[9]=v2.y; xv[10]=v2.z; xv[11]=v2.w;
    xv[12]=v3.x; xv[13]=v3.y; xv[14]=v3.z; xv[15]=v3.w;
  }

  for (int blk = 0; blk < T_LEN / 16; ++blk) {
    // Prefetch next block of x (wraps to 0 on last iter; values unused)
    float xn[16];
    {
      const int nb = (blk + 1) & (T_LEN / 16 - 1);
      const float4* p4 = reinterpret_cast<const float4*>(xb + nb * 16);
      float4 v0 = p4[0], v1 = p4[1], v2 = p4[2], v3 = p4[3];
      xn[0]=v0.x; xn[1]=v0.y; xn[2]=v0.z; xn[3]=v0.w;
      xn[4]=v1.x; xn[5]=v1.y; xn[6]=v1.z; xn[7]=v1.w;
      xn[8]=v2.x; xn[9]=v2.y; xn[10]=v2.z; xn[11]=v2.w;
      xn[12]=v3.x; xn[13]=v3.y; xn[14]=v3.z; xn[15]=v3.w;
    }

    GSTEP(0);  GSTEP(1);  GSTEP(2);  GSTEP(3);
    GSTEP(4);  GSTEP(5);  GSTEP(6);  GSTEP(7);
    GSTEP(8);  GSTEP(9);  GSTEP(10); GSTEP(11);
    GSTEP(12); GSTEP(13); GSTEP(14); GSTEP(15);

    // lane j holds y for t = blk*16 + j -> coalesced 64B store per group
    yb[blk * 16 + j] = ykeep;

#pragma unroll
    for (int m = 0; m < 16; ++m) xv[m] = xn[m];
  }
}

extern "C" void kernel_launch(void* const* d_in, const int* in_sizes, int n_in,
                              void* d_out, int out_size, void* d_ws, size_t ws_size,
                              hipStream_t stream) {
  const float* x    = (const float*)d_in[0];
  const float* W_ih = (const float*)d_in[1];
  const float* W_hh = (const float*)d_in[2];
  const float* b_ih = (const float*)d_in[3];
  const float* b_hh = (const float*)d_in[4];
  const float* W_fc = (const float*)d_in[5];
  const float* b_fc = (const float*)d_in[6];
  float* out = (float*)d_out;

  // 4096 sequences / 4 per wave = 1024 waves = 65536 threads
  dim3 grid(256), block(256);
  hipLaunchKernelGGL(lstm_fused_kernel, grid, block, 0, stream,
                     x, W_ih, W_hh, b_ih, b_hh, W_fc, b_fc, out);
}

// Round 2
// 440.908 us; speedup vs baseline: 1.0888x; 1.0888x over previous
//
#include <hip/hip_runtime.h>

// LSTM: B=4096, T=2048, I=1, H=16. 16 lanes per sequence (lane j owns h[j],c[j]
// and gate rows j, j+16, j+32, j+48), 4 sequences per wave64. All cross-lane
// traffic via DPP (quad_perm / row mirrors) - zero LDS. fp32 throughout.
// R1: __launch_bounds__(256,1) to kill AGPR spills (we can only occupy
// 1 wave/SIMD anyway); gate accumulation packed into float2 -> v_pk_fma_f32
// (2 FMAs/instr, the CDNA4 dual-issue fp32 path).

constexpr int T_LEN = 2048;

typedef float v2f __attribute__((ext_vector_type(2)));

template<int CTRL>
__device__ __forceinline__ float dpp_mov(float v) {
  return __int_as_float(__builtin_amdgcn_update_dpp(
      0, __float_as_int(v), CTRL, 0xF, 0xF, true));
}

__device__ __forceinline__ float fexp2(float x) { return __builtin_amdgcn_exp2f(x); }
__device__ __forceinline__ float frcp(float x)  { return __builtin_amdgcn_rcpf(x); }
// sigmoid(x) = 1/(1+2^(-x*log2e))
__device__ __forceinline__ float fsig(float x)  { return frcp(1.0f + fexp2(x * -1.4426950408889634f)); }
// tanh(x) = 2/(1+2^(-2x*log2e)) - 1
__device__ __forceinline__ float ftanh_(float x){ return fmaf(frcp(1.0f + fexp2(x * -2.8853900817779268f)), 2.0f, -1.0f); }

// DPP ctrl values:
//  0xB1 = quad_perm [1,0,3,2]  -> lane ^ 1
//  0x4E = quad_perm [2,3,0,1]  -> lane ^ 2
//  0x1B = quad_perm [3,2,1,0]  -> lane ^ 3
//  0x141 = row_half_mirror     -> lane ^ 7  (within 8)
//  0x140 = row_mirror          -> lane ^ 15 (within 16)

// One packed xor-walk round: advance rotation twice (m=2P, 2P+1) into the
// lo/hi halves of hp, then 4 packed FMAs (one per gate).
#define PKROUND(CTRL_A, CTRL_B, P) do {                                    \
    hc = dpp_mov<CTRL_A>(hc); hp.x = hc;                                   \
    hc = dpp_mov<CTRL_B>(hc); hp.y = hc;                                   \
    a0p = hp * w0p[P] + a0p; a1p = hp * w1p[P] + a1p;                      \
    a2p = hp * w2p[P] + a2p; a3p = hp * w3p[P] + a3p;                      \
  } while (0)

// One LSTM timestep (S = step-in-block, compile-time literal).
#define GSTEP(S) do {                                                      \
    const float xt = xv[S];                                                \
    v2f a0p; a0p.x = fmaf(xt, wih0, bb0); a0p.y = 0.0f;                    \
    v2f a1p; a1p.x = fmaf(xt, wih1, bb1); a1p.y = 0.0f;                    \
    v2f a2p; a2p.x = fmaf(xt, wih2, bb2); a2p.y = 0.0f;                    \
    v2f a3p; a3p.x = fmaf(xt, wih3, bb3); a3p.y = 0.0f;                    \
    float hc = h;                                                          \
    v2f hp; hp.x = hc;                                                     \
    hc = dpp_mov<0xB1>(hc); hp.y = hc;                                     \
    a0p = hp * w0p[0] + a0p; a1p = hp * w1p[0] + a1p;                      \
    a2p = hp * w2p[0] + a2p; a3p = hp * w3p[0] + a3p;                      \
    PKROUND(0x1B,  0xB1, 1);                                               \
    PKROUND(0x141, 0xB1, 2);                                               \
    PKROUND(0x1B,  0xB1, 3);                                               \
    PKROUND(0x140, 0xB1, 4);                                               \
    PKROUND(0x1B,  0xB1, 5);                                               \
    PKROUND(0x141, 0xB1, 6);                                               \
    PKROUND(0x1B,  0xB1, 7);                                               \
    const float a0 = a0p.x + a0p.y;                                        \
    const float a1 = a1p.x + a1p.y;                                        \
    const float a2 = a2p.x + a2p.y;                                        \
    const float a3 = a3p.x + a3p.y;                                        \
    const float iv = fsig(a0);                                             \
    const float fv = fsig(a1);                                             \
    const float gv = ftanh_(a2);                                           \
    const float ov = fsig(a3);                                             \
    c = fmaf(fv, c, iv * gv);                                              \
    h = ov * ftanh_(c);                                                    \
    float p = h * wfcj;                                                    \
    p += dpp_mov<0xB1>(p);                                                 \
    p += dpp_mov<0x4E>(p);                                                 \
    p += dpp_mov<0x141>(p);                                                \
    p += dpp_mov<0x140>(p);                                                \
    ykeep = (j == (S)) ? (p + bfc) : ykeep;                                \
  } while (0)

__global__ __launch_bounds__(256, 1) void lstm_fused_kernel(
    const float* __restrict__ x, const float* __restrict__ W_ih,
    const float* __restrict__ W_hh, const float* __restrict__ b_ih,
    const float* __restrict__ b_hh, const float* __restrict__ W_fc,
    const float* __restrict__ b_fc, float* __restrict__ out)
{
  const int tid  = blockIdx.x * blockDim.x + threadIdx.x;
  const int wave = tid >> 6;          // 0..1023
  const int lane = tid & 63;
  const int grp  = (lane >> 4) & 3;   // sequence-within-wave
  const int j    = lane & 15;         // h index owned by this lane
  const int b    = wave * 4 + grp;    // sequence id 0..4095

  const float* __restrict__ xb = x   + (size_t)b * T_LEN;
  float*       __restrict__ yb = out + (size_t)b * T_LEN;

  const int r0 = j, r1 = j + 16, r2 = j + 32, r3 = j + 48;

  // Pre-gathered, xor-permuted W_hh rows, packed over m-pairs:
  // wXp[p] = { W_hh[r][j^(2p)], W_hh[r][j^(2p+1)] }
  v2f w0p[8], w1p[8], w2p[8], w3p[8];
#pragma unroll
  for (int p = 0; p < 8; ++p) {
    const int ka = j ^ (2 * p), kb = j ^ (2 * p + 1);
    w0p[p].x = W_hh[r0 * 16 + ka]; w0p[p].y = W_hh[r0 * 16 + kb];
    w1p[p].x = W_hh[r1 * 16 + ka]; w1p[p].y = W_hh[r1 * 16 + kb];
    w2p[p].x = W_hh[r2 * 16 + ka]; w2p[p].y = W_hh[r2 * 16 + kb];
    w3p[p].x = W_hh[r3 * 16 + ka]; w3p[p].y = W_hh[r3 * 16 + kb];
  }
  const float wih0 = W_ih[r0], wih1 = W_ih[r1], wih2 = W_ih[r2], wih3 = W_ih[r3];
  const float bb0 = b_ih[r0] + b_hh[r0];
  const float bb1 = b_ih[r1] + b_hh[r1];
  const float bb2 = b_ih[r2] + b_hh[r2];
  const float bb3 = b_ih[r3] + b_hh[r3];
  const float wfcj = W_fc[j];
  const float bfc  = b_fc[0];

  float h = 0.0f, c = 0.0f, ykeep = 0.0f;

  // x for current 16-step block, in registers (group-uniform loads -> cache bcast)
  float xv[16];
  {
    const float4* p4 = reinterpret_cast<const float4*>(xb);
    float4 v0 = p4[0], v1 = p4[1], v2 = p4[2], v3 = p4[3];
    xv[0]=v0.x; xv[1]=v0.y; xv[2]=v0.z; xv[3]=v0.w;
    xv[4]=v1.x; xv[5]=v1.y; xv[6]=v1.z; xv[7]=v1.w;
    xv[8]=v2.x; xv[9]=v2.y; xv[10]=v2.z; xv[11]=v2.w;
    xv[12]=v3.x; xv[13]=v3.y; xv[14]=v3.z; xv[15]=v3.w;
  }

  for (int blk = 0; blk < T_LEN / 16; ++blk) {
    // Prefetch next block of x (wraps to 0 on last iter; values unused)
    float xn[16];
    {
      const int nb = (blk + 1) & (T_LEN / 16 - 1);
      const float4* p4 = reinterpret_cast<const float4*>(xb + nb * 16);
      float4 v0 = p4[0], v1 = p4[1], v2 = p4[2], v3 = p4[3];
      xn[0]=v0.x; xn[1]=v0.y; xn[2]=v0.z; xn[3]=v0.w;
      xn[4]=v1.x; xn[5]=v1.y; xn[6]=v1.z; xn[7]=v1.w;
      xn[8]=v2.x; xn[9]=v2.y; xn[10]=v2.z; xn[11]=v2.w;
      xn[12]=v3.x; xn[13]=v3.y; xn[14]=v3.z; xn[15]=v3.w;
    }

    GSTEP(0);  GSTEP(1);  GSTEP(2);  GSTEP(3);
    GSTEP(4);  GSTEP(5);  GSTEP(6);  GSTEP(7);
    GSTEP(8);  GSTEP(9);  GSTEP(10); GSTEP(11);
    GSTEP(12); GSTEP(13); GSTEP(14); GSTEP(15);

    // lane j holds y for t = blk*16 + j -> coalesced 64B store per group
    yb[blk * 16 + j] = ykeep;

#pragma unroll
    for (int m = 0; m < 16; ++m) xv[m] = xn[m];
  }
}

extern "C" void kernel_launch(void* const* d_in, const int* in_sizes, int n_in,
                              void* d_out, int out_size, void* d_ws, size_t ws_size,
                              hipStream_t stream) {
  const float* x    = (const float*)d_in[0];
  const float* W_ih = (const float*)d_in[1];
  const float* W_hh = (const float*)d_in[2];
  const float* b_ih = (const float*)d_in[3];
  const float* b_hh = (const float*)d_in[4];
  const float* W_fc = (const float*)d_in[5];
  const float* b_fc = (const float*)d_in[6];
  float* out = (float*)d_out;

  // 4096 sequences / 4 per wave = 1024 waves = 65536 threads
  dim3 grid(256), block(256);
  hipLaunchKernelGGL(lstm_fused_kernel, grid, block, 0, stream,
                     x, W_ih, W_hh, b_ih, b_hh, W_fc, b_fc, out);
}

// Round 3
// 361.996 us; speedup vs baseline: 1.3262x; 1.2180x over previous
//
#include <hip/hip_runtime.h>

// LSTM: B=4096, T=2048, I=1, H=16. 16 lanes/seq, 4 seqs/wave64, zero LDS.
// R2: h@W_hh via v_dot2_f32_f16 (fp16 mul, fp32 acc, FULL rate = 2 MAC/lane/cyc;
// fp32 fma is 1 MAC/lane/cyc and pk_fma_f32 is half-rate so packing fp32 was a
// wash). Packed-pair xor-walk: 8 dot2-rounds/gate, 10 DPPs total. Activation
// scale -log2e (and -2log2e for g) pre-folded into weights/biases so each
// sigmoid/tanh is exp2+add+rcp. 2x unrolled x double-buffer.

constexpr int T_LEN = 2048;

typedef _Float16 h2 __attribute__((ext_vector_type(2)));

template<int CTRL>
__device__ __forceinline__ unsigned dpp_u32(unsigned v) {
  return (unsigned)__builtin_amdgcn_update_dpp(0, (int)v, CTRL, 0xF, 0xF, true);
}
template<int CTRL>
__device__ __forceinline__ float dpp_f32(float v) {
  return __int_as_float(__builtin_amdgcn_update_dpp(
      0, __float_as_int(v), CTRL, 0xF, 0xF, true));
}

__device__ __forceinline__ float fexp2(float x) { return __builtin_amdgcn_exp2f(x); }
__device__ __forceinline__ float frcp(float x)  { return __builtin_amdgcn_rcpf(x); }
__device__ __forceinline__ h2 u2h(unsigned u) { union { unsigned u; h2 h; } c; c.u = u; return c.h; }

// DPP ctrl: 0xB1=^1  0x4E=^2  0x1B=^3  0x141=^7  0x140=^15

#define DOT4(P) do {                                                       \
    a0 = __builtin_amdgcn_fdot2(u2h(cur), w0p[P], a0, false);              \
    a1 = __builtin_amdgcn_fdot2(u2h(cur), w1p[P], a1, false);              \
    a2 = __builtin_amdgcn_fdot2(u2h(cur), w2p[P], a2, false);              \
    a3 = __builtin_amdgcn_fdot2(u2h(cur), w3p[P], a3, false);              \
  } while (0)

// One LSTM timestep. S = step-in-block literal, XV = x register buffer.
#define GSTEP(S, XV) do {                                                  \
    const float xt = XV[S];                                                \
    float a0 = fmaf(xt, wih0, bb0);                                        \
    float a1 = fmaf(xt, wih1, bb1);                                        \
    float a2 = fmaf(xt, wih2, bb2);                                        \
    float a3 = fmaf(xt, wih3, bb3);                                        \
    unsigned hu; { union { _Float16 f; unsigned short s; } cc;             \
      cc.f = (_Float16)h; hu = cc.s; }                                     \
    unsigned hn = dpp_u32<0xB1>(hu);                                       \
    unsigned cur = __builtin_amdgcn_perm(hn, hu, 0x05040100);              \
    DOT4(0);                                                               \
    cur = dpp_u32<0x4E>(cur);                              DOT4(1);        \
    cur = dpp_u32<0x141>(cur); cur = dpp_u32<0xB1>(cur);   DOT4(2);        \
    cur = dpp_u32<0x4E>(cur);                              DOT4(3);        \
    cur = dpp_u32<0x140>(cur); cur = dpp_u32<0xB1>(cur);   DOT4(4);        \
    cur = dpp_u32<0x4E>(cur);                              DOT4(5);        \
    cur = dpp_u32<0x141>(cur); cur = dpp_u32<0xB1>(cur);   DOT4(6);        \
    cur = dpp_u32<0x4E>(cur);                              DOT4(7);        \
    const float iv = frcp(1.0f + fexp2(a0));                               \
    const float fv = frcp(1.0f + fexp2(a1));                               \
    const float gv = fmaf(frcp(1.0f + fexp2(a2)), 2.0f, -1.0f);            \
    const float ov = frcp(1.0f + fexp2(a3));                               \
    c = fmaf(fv, c, iv * gv);                                              \
    const float th = fmaf(frcp(1.0f + fexp2(c * KG)), 2.0f, -1.0f);        \
    h = ov * th;                                                           \
    float p_ = h * wfcj;                                                   \
    p_ += dpp_f32<0xB1>(p_);                                               \
    p_ += dpp_f32<0x4E>(p_);                                               \
    p_ += dpp_f32<0x141>(p_);                                              \
    p_ += dpp_f32<0x140>(p_);                                              \
    ykeep = (j == (S)) ? (p_ + bfc) : ykeep;                               \
  } while (0)

#define LOAD16(DST, BLK) do {                                              \
    const float4* p4 = reinterpret_cast<const float4*>(xb + (BLK) * 16);   \
    float4 v0 = p4[0], v1 = p4[1], v2 = p4[2], v3 = p4[3];                 \
    DST[0]=v0.x;  DST[1]=v0.y;  DST[2]=v0.z;  DST[3]=v0.w;                 \
    DST[4]=v1.x;  DST[5]=v1.y;  DST[6]=v1.z;  DST[7]=v1.w;                 \
    DST[8]=v2.x;  DST[9]=v2.y;  DST[10]=v2.z; DST[11]=v2.w;                \
    DST[12]=v3.x; DST[13]=v3.y; DST[14]=v3.z; DST[15]=v3.w;                \
  } while (0)

__global__ __launch_bounds__(256, 1) void lstm_fused_kernel(
    const float* __restrict__ x, const float* __restrict__ W_ih,
    const float* __restrict__ W_hh, const float* __restrict__ b_ih,
    const float* __restrict__ b_hh, const float* __restrict__ W_fc,
    const float* __restrict__ b_fc, float* __restrict__ out)
{
  const int tid  = blockIdx.x * blockDim.x + threadIdx.x;
  const int wave = tid >> 6;
  const int lane = tid & 63;
  const int grp  = (lane >> 4) & 3;
  const int j    = lane & 15;
  const int b    = wave * 4 + grp;

  const float* __restrict__ xb = x   + (size_t)b * T_LEN;
  float*       __restrict__ yb = out + (size_t)b * T_LEN;

  const int r0 = j, r1 = j + 16, r2 = j + 32, r3 = j + 48;

  // Pre-scale: sigmoid rows (i,f,o) by -log2e; tanh rows (g) by -2log2e.
  constexpr float KN = -1.4426950408889634f;
  constexpr float KG = -2.8853900817779268f;
  const float s0 = KN, s1 = KN, s2 = KG, s3 = KN;

  // Pre-gathered, xor-permuted, pre-scaled f16 weight pairs:
  // wXp[p] = { W[r][j^2p]*s, W[r][j^2p^1]*s }
  h2 w0p[8], w1p[8], w2p[8], w3p[8];
#pragma unroll
  for (int p = 0; p < 8; ++p) {
    const int ka = j ^ (2 * p), kb = (j ^ (2 * p)) ^ 1;
    w0p[p] = h2{(_Float16)(W_hh[r0 * 16 + ka] * s0), (_Float16)(W_hh[r0 * 16 + kb] * s0)};
    w1p[p] = h2{(_Float16)(W_hh[r1 * 16 + ka] * s1), (_Float16)(W_hh[r1 * 16 + kb] * s1)};
    w2p[p] = h2{(_Float16)(W_hh[r2 * 16 + ka] * s2), (_Float16)(W_hh[r2 * 16 + kb] * s2)};
    w3p[p] = h2{(_Float16)(W_hh[r3 * 16 + ka] * s3), (_Float16)(W_hh[r3 * 16 + kb] * s3)};
  }
  const float wih0 = W_ih[r0] * s0, wih1 = W_ih[r1] * s1;
  const float wih2 = W_ih[r2] * s2, wih3 = W_ih[r3] * s3;
  const float bb0 = (b_ih[r0] + b_hh[r0]) * s0;
  const float bb1 = (b_ih[r1] + b_hh[r1]) * s1;
  const float bb2 = (b_ih[r2] + b_hh[r2]) * s2;
  const float bb3 = (b_ih[r3] + b_hh[r3]) * s3;
  const float wfcj = W_fc[j];
  const float bfc  = b_fc[0];

  float h = 0.0f, c = 0.0f, ykeep = 0.0f;

  float xv[16], xn[16];
  LOAD16(xv, 0);

  constexpr int NB = T_LEN / 16;  // 128 blocks of 16 steps
  for (int it = 0; it < NB / 2; ++it) {
    const int blkA = 2 * it, blkB = 2 * it + 1;

    LOAD16(xn, blkB);
    GSTEP(0, xv);  GSTEP(1, xv);  GSTEP(2, xv);  GSTEP(3, xv);
    GSTEP(4, xv);  GSTEP(5, xv);  GSTEP(6, xv);  GSTEP(7, xv);
    GSTEP(8, xv);  GSTEP(9, xv);  GSTEP(10, xv); GSTEP(11, xv);
    GSTEP(12, xv); GSTEP(13, xv); GSTEP(14, xv); GSTEP(15, xv);
    yb[blkA * 16 + j] = ykeep;

    LOAD16(xv, (blkB + 1) & (NB - 1));  // wraps on last iter; unused
    GSTEP(0, xn);  GSTEP(1, xn);  GSTEP(2, xn);  GSTEP(3, xn);
    GSTEP(4, xn);  GSTEP(5, xn);  GSTEP(6, xn);  GSTEP(7, xn);
    GSTEP(8, xn);  GSTEP(9, xn);  GSTEP(10, xn); GSTEP(11, xn);
    GSTEP(12, xn); GSTEP(13, xn); GSTEP(14, xn); GSTEP(15, xn);
    yb[blkB * 16 + j] = ykeep;
  }
}

extern "C" void kernel_launch(void* const* d_in, const int* in_sizes, int n_in,
                              void* d_out, int out_size, void* d_ws, size_t ws_size,
                              hipStream_t stream) {
  const float* x    = (const float*)d_in[0];
  const float* W_ih = (const float*)d_in[1];
  const float* W_hh = (const float*)d_in[2];
  const float* b_ih = (const float*)d_in[3];
  const float* b_hh = (const float*)d_in[4];
  const float* W_fc = (const float*)d_in[5];
  const float* b_fc = (const float*)d_in[6];
  float* out = (float*)d_out;

  dim3 grid(256), block(256);
  hipLaunchKernelGGL(lstm_fused_kernel, grid, block, 0, stream,
                     x, W_ih, W_hh, b_ih, b_hh, W_fc, b_fc, out);
}